// Round 3
// baseline (564.957 us; speedup 1.0000x reference)
//
#include <hip/hip_runtime.h>
#include <hip/hip_bf16.h>

#define B_DIM 32
#define C_DIM 256
#define H_DIM 128
#define W_DIM 256
#define ATT_DIM 256
#define G_CHUNK 8                      // batches per chunk (268 MB of feat ~ L3)
#define N_CHUNK (B_DIM / G_CHUNK)

// ---------------------------------------------------------------------------
// KA(g): heterogeneous chunk kernel for batches [b0, b0+G).
//   blocks [0, G*256):        pool+width for (b = b0 + bid/256, c = bid%256)
//   blocks [G*256, G*256+G):  InstanceNorm + Conv1d for batch b0+i
//   blocks [+G, +2G):         hidden GEMV + fused biases for batch b0+i
__global__ __launch_bounds__(256) void ka_chunk(
    const float* __restrict__ feat, const float* __restrict__ w_width,
    const float* __restrict__ b_width,
    const float* __restrict__ prev, const float* __restrict__ cov,
    const float* __restrict__ conv_w, const float* __restrict__ conv_b,
    const float* __restrict__ hidden, const float* __restrict__ w_hid,
    const float* __restrict__ b_hid, const float* __restrict__ b_enc,
    const float* __restrict__ b_cb,
    float* __restrict__ hf, float* __restrict__ convT, float* __restrict__ hsum,
    int b0)
{
  const int tid = threadIdx.x;
  const int bid = blockIdx.x;
  const int NPOOL = G_CHUNK * C_DIM;

  if (bid < NPOOL) {
    // ---- pool+width: one block per (b,c); 4 waves x 32 rows of 256 floats ----
    __shared__ float res[H_DIM];
    const int lane = tid & 63, wid = tid >> 6;
    const int bc = b0 * C_DIM + bid;              // global b*C + c
    const float wv = w_width[lane >> 1] * 0.5f;   // halved: pair-max counted twice
    const float bw = b_width[0];
    const float* base = feat + (size_t)bc * H_DIM * W_DIM + lane * 4;
#pragma unroll 4
    for (int i = 0; i < 32; i++) {
      const int h = wid + 4 * i;
      float4 v4 = *reinterpret_cast<const float4*>(base + (size_t)h * W_DIM);
      float v = fmaxf(fmaxf(v4.x, v4.y), fmaxf(v4.z, v4.w));
      v = fmaxf(v, __shfl_xor(v, 1));             // 8-wide window max (2 lanes)
      float contrib = v * wv;
#pragma unroll
      for (int off = 32; off >= 1; off >>= 1) contrib += __shfl_xor(contrib, off);
      if (lane == 0) res[h] = contrib + bw;
    }
    __syncthreads();
    if (tid < H_DIM)
      hf[(size_t)bc * H_DIM + tid] = res[tid];    // coalesced 512B store
  } else if (bid < NPOOL + G_CHUNK) {
    // ---- InstanceNorm1d(2ch over H) + Conv1d(2->16,k15,p7) ----
    const int b = b0 + (bid - NPOOL);
    __shared__ float n0[H_DIM], n1[H_DIM];
    __shared__ float ws4[2][4];
    __shared__ float cw[480];
    for (int i = tid; i < 480; i += 256) cw[i] = conv_w[i];
    const int lane = tid & 63, wv2 = tid >> 6;
    float x0 = 0.f, x1 = 0.f;
    if (tid < 128) {
      x0 = prev[b * H_DIM + tid];
      x1 = cov[b * H_DIM + tid];
      x1 = fminf(fmaxf(x1, 0.0f), 1.0f);
      float s0 = x0, q0 = x0 * x0, s1 = x1, q1 = x1 * x1;
#pragma unroll
      for (int off = 32; off >= 1; off >>= 1) {
        s0 += __shfl_xor(s0, off); q0 += __shfl_xor(q0, off);
        s1 += __shfl_xor(s1, off); q1 += __shfl_xor(q1, off);
      }
      if (lane == 0) { ws4[wv2][0] = s0; ws4[wv2][1] = q0; ws4[wv2][2] = s1; ws4[wv2][3] = q1; }
    }
    __syncthreads();
    if (tid < 128) {
      float S0 = ws4[0][0] + ws4[1][0], Q0 = ws4[0][1] + ws4[1][1];
      float S1 = ws4[0][2] + ws4[1][2], Q1 = ws4[0][3] + ws4[1][3];
      const float rH = 1.0f / H_DIM;
      float mu0 = S0 * rH, mu1 = S1 * rH;
      float inv0 = 1.0f / sqrtf(Q0 * rH - mu0 * mu0 + 1e-5f);
      float inv1 = 1.0f / sqrtf(Q1 * rH - mu1 * mu1 + 1e-5f);
      n0[tid] = (x0 - mu0) * inv0;
      n1[tid] = (x1 - mu1) * inv1;
    }
    __syncthreads();
    if (tid < 128) {
      float o[16];
#pragma unroll
      for (int k = 0; k < 16; k++) o[k] = conv_b[k];
#pragma unroll
      for (int j = 0; j < 15; j++) {
        int hh = tid - 7 + j;
        if (hh >= 0 && hh < H_DIM) {
          float f0 = n0[hh], f1 = n1[hh];
#pragma unroll
          for (int k = 0; k < 16; k++)
            o[k] += f0 * cw[k * 30 + j] + f1 * cw[k * 30 + 15 + j];
        }
      }
      float* outp = convT + ((size_t)(b * H_DIM + tid)) * 16;
#pragma unroll
      for (int k = 0; k < 16; k++) outp[k] = o[k];
    }
  } else {
    // ---- hsum[b,a] = hidden[b,:] @ w_hid[:,a] + b_hid + b_enc + b_cb ----
    const int b = b0 + (bid - NPOOL - G_CHUNK);
    const int a = tid;
    float acc = b_hid[a] + b_enc[a] + b_cb[a];
    const float* hb = hidden + b * 256;
#pragma unroll 4
    for (int d = 0; d < 256; d++) acc += hb[d] * w_hid[d * ATT_DIM + a];
    hsum[b * ATT_DIM + a] = acc;
  }
}

// ---------------------------------------------------------------------------
// KB(g): s = hf^T @ w_enc + convT @ w_cb + hsum; align = tanh(s)@w_align + b
// 8 rows x 256 cols per block; thread t owns column a=t.  hf is (B,C,H).
__global__ __launch_bounds__(256) void kb_chunk(
    const float* __restrict__ hf, const float* __restrict__ convT,
    const float* __restrict__ hsum, const float* __restrict__ w_enc,
    const float* __restrict__ w_cb, const float* __restrict__ w_align,
    const float* __restrict__ b_align, float* __restrict__ align_out, int b0)
{
  __shared__ float At[C_DIM][12];   // [k=c][m], pitch 12 keeps float4 alignment
  __shared__ float Ct[16][9];       // [k][m]
  __shared__ float red[8][ATT_DIM];
  const int tid = threadIdx.x;
  const int m0 = b0 * H_DIM + blockIdx.x * 8;   // global row (b*H + h)
  const int b = m0 >> 7;
  const int h0 = m0 & 127;
  const float* hp = hf + ((size_t)(b * C_DIM + tid)) * H_DIM + h0;
  float4 r0 = *reinterpret_cast<const float4*>(hp);
  float4 r1 = *reinterpret_cast<const float4*>(hp + 4);
  *reinterpret_cast<float4*>(&At[tid][0]) = r0;
  *reinterpret_cast<float4*>(&At[tid][4]) = r1;
  if (tid < 128) {
    int m = tid >> 4, k = tid & 15;
    Ct[k][m] = convT[(size_t)(b * H_DIM + h0) * 16 + tid];
  }
  __syncthreads();
  float acc[8];
#pragma unroll
  for (int m = 0; m < 8; m++) acc[m] = 0.0f;
  const float* wep = w_enc + tid;
#pragma unroll 4
  for (int k = 0; k < C_DIM; k++) {
    float bv = wep[k * ATT_DIM];
    const float4 a0 = *reinterpret_cast<const float4*>(&At[k][0]);
    const float4 a1 = *reinterpret_cast<const float4*>(&At[k][4]);
    acc[0] += a0.x * bv; acc[1] += a0.y * bv; acc[2] += a0.z * bv; acc[3] += a0.w * bv;
    acc[4] += a1.x * bv; acc[5] += a1.y * bv; acc[6] += a1.z * bv; acc[7] += a1.w * bv;
  }
#pragma unroll
  for (int k = 0; k < 16; k++) {
    float bv = w_cb[k * ATT_DIM + tid];
#pragma unroll
    for (int m = 0; m < 8; m++) acc[m] += Ct[k][m] * bv;
  }
  const float hs = hsum[b * ATT_DIM + tid];
  const float wa = w_align[tid];
#pragma unroll
  for (int m = 0; m < 8; m++)
    red[m][tid] = tanhf(acc[m] + hs) * wa;
  __syncthreads();
  const int lane = tid & 63, wid = tid >> 6;
  const float ba = b_align[0];
  for (int m = wid; m < 8; m += 4) {
    float s = red[m][lane] + red[m][lane + 64] + red[m][lane + 128] + red[m][lane + 192];
#pragma unroll
    for (int off = 32; off >= 1; off >>= 1) s += __shfl_xor(s, off);
    if (lane == 0) align_out[m0 + m] = s + ba;
  }
}

// ---------------------------------------------------------------------------
// KC(g): in-block softmax over H + context reduce for the chunk's batches.
// Reverse block order within chunk: reads the feat lines KA(g) cached last.
__global__ __launch_bounds__(256) void kc_chunk(
    const float* __restrict__ feat, const float* __restrict__ align,
    float* __restrict__ attn_out, float* __restrict__ ctx, int b0)
{
  const int bc = b0 * C_DIM + (G_CHUNK * C_DIM - 1 - blockIdx.x);  // reversed
  const int b = bc >> 8, c = bc & 255;
  const int tid = threadIdx.x;
  __shared__ float al[H_DIM], at[H_DIM];
  if (tid < H_DIM) al[tid] = align[(b << 7) + tid];
  __syncthreads();
  if (tid < 64) {
    float a0 = al[tid], a1 = al[tid + 64];
    float mx = fmaxf(a0, a1);
#pragma unroll
    for (int off = 32; off >= 1; off >>= 1) mx = fmaxf(mx, __shfl_xor(mx, off));
    float e0 = expf(a0 - mx), e1 = expf(a1 - mx);
    float s = e0 + e1;
#pragma unroll
    for (int off = 32; off >= 1; off >>= 1) s += __shfl_xor(s, off);
    float inv = 1.0f / s;
    at[tid] = e0 * inv;
    at[tid + 64] = e1 * inv;
  }
  __syncthreads();
  if (c == 0 && tid < H_DIM) attn_out[(b << 7) + tid] = at[tid];
  const int g = tid >> 6, lane = tid & 63;
  const float* base = feat + (size_t)bc * H_DIM * W_DIM + lane * 4;
  float4 acc = make_float4(0.f, 0.f, 0.f, 0.f);
#pragma unroll 4
  for (int h = g; h < H_DIM; h += 4) {
    float4 v = *reinterpret_cast<const float4*>(base + (size_t)h * W_DIM);
    float a = at[h];
    acc.x += v.x * a; acc.y += v.y * a; acc.z += v.z * a; acc.w += v.w * a;
  }
  __shared__ float4 part[4][64];
  part[g][lane] = acc;
  __syncthreads();
  if (tid < 64) {
    float4 r0 = part[0][tid], r1 = part[1][tid], r2 = part[2][tid], r3 = part[3][tid];
    float4 o;
    o.x = r0.x + r1.x + r2.x + r3.x;
    o.y = r0.y + r1.y + r2.y + r3.y;
    o.z = r0.z + r1.z + r2.z + r3.z;
    o.w = r0.w + r1.w + r2.w + r3.w;
    *reinterpret_cast<float4*>(ctx + (size_t)bc * W_DIM + tid * 4) = o;
  }
}

// ---------------------------------------------------------------------------
extern "C" void kernel_launch(void* const* d_in, const int* in_sizes, int n_in,
                              void* d_out, int out_size, void* d_ws, size_t ws_size,
                              hipStream_t stream)
{
  const float* feat    = (const float*)d_in[0];
  const float* prev    = (const float*)d_in[1];
  const float* cov     = (const float*)d_in[2];
  const float* hidden  = (const float*)d_in[3];
  const float* w_width = (const float*)d_in[4];
  const float* b_width = (const float*)d_in[5];
  const float* w_enc   = (const float*)d_in[6];
  const float* b_enc   = (const float*)d_in[7];
  const float* conv_w  = (const float*)d_in[8];
  const float* conv_b  = (const float*)d_in[9];
  const float* w_cb    = (const float*)d_in[10];
  const float* b_cb    = (const float*)d_in[11];
  const float* w_hid   = (const float*)d_in[12];
  const float* b_hid   = (const float*)d_in[13];
  const float* w_align = (const float*)d_in[14];
  const float* b_align = (const float*)d_in[15];

  float* ctx_out  = (float*)d_out;                                   // (B,C,W)
  float* attn_out = (float*)d_out + (size_t)B_DIM * C_DIM * W_DIM;   // (B,H)

  float* ws    = (float*)d_ws;
  float* hf    = ws;                 // (B,C,H)  = 1048576 floats
  float* convT = hf + 1048576;       // (B,H,16) = 65536
  float* hsum  = convT + 65536;      // (B,ATT)  = 8192
  float* align = hsum + 8192;        // (B,H)    = 4096

  for (int g = 0; g < N_CHUNK; ++g) {
    const int b0 = g * G_CHUNK;
    ka_chunk<<<dim3(G_CHUNK * C_DIM + 2 * G_CHUNK), dim3(256), 0, stream>>>(
        feat, w_width, b_width, prev, cov, conv_w, conv_b,
        hidden, w_hid, b_hid, b_enc, b_cb, hf, convT, hsum, b0);
    kb_chunk<<<dim3(G_CHUNK * H_DIM / 8), dim3(256), 0, stream>>>(
        hf, convT, hsum, w_enc, w_cb, w_align, b_align, align, b0);
    kc_chunk<<<dim3(G_CHUNK * C_DIM), dim3(256), 0, stream>>>(
        feat, align, attn_out, ctx_out, b0);
  }
}

// Round 4
// 400.650 us; speedup vs baseline: 1.4101x; 1.4101x over previous
//
#include <hip/hip_runtime.h>
#include <hip/hip_bf16.h>

#define B_DIM 32
#define C_DIM 256
#define H_DIM 128
#define W_DIM 256
#define ATT_DIM 256

// ---------------------------------------------------------------------------
// KA: heterogeneous fused kernel.
//   blocks [0, 8192):     pool+width for (b,c)=bid -> hf in (B,C,H) layout
//   blocks [8192, 8224):  InstanceNorm + Conv1d for b=bid-8192 -> convT (B,H,16)
//   blocks [8224, 8256):  hidden GEMV + fused biases for b=bid-8224 -> hsum
__global__ __launch_bounds__(256) void ka_fused(
    const float* __restrict__ feat, const float* __restrict__ w_width,
    const float* __restrict__ b_width,
    const float* __restrict__ prev, const float* __restrict__ cov,
    const float* __restrict__ conv_w, const float* __restrict__ conv_b,
    const float* __restrict__ hidden, const float* __restrict__ w_hid,
    const float* __restrict__ b_hid, const float* __restrict__ b_enc,
    const float* __restrict__ b_cb,
    float* __restrict__ hf, float* __restrict__ convT, float* __restrict__ hsum)
{
  const int tid = threadIdx.x;
  const int bid = blockIdx.x;

  if (bid < 8192) {
    // ---- pool+width: one block per (b,c); lane owns one 8-float window ----
    // Wave w handles rows [32w, 32w+32), 2 rows/iter (2KB contiguous/wave).
    __shared__ float res[H_DIM];
    const int lane = tid & 63, w = tid >> 6;
    const int half = lane >> 5;          // which row of the pair
    const int m = lane & 31;             // window index
    const float wv = w_width[m];
    const float bw = b_width[0];
    const float* base = feat + (size_t)bid * H_DIM * W_DIM + m * 8;
#pragma unroll 4
    for (int i = 0; i < 16; i++) {
      const int h = w * 32 + i * 2 + half;
      const float4* p = reinterpret_cast<const float4*>(base + (size_t)h * W_DIM);
      float4 a = p[0], b2 = p[1];
      float mx = fmaxf(fmaxf(fmaxf(a.x, a.y), fmaxf(a.z, a.w)),
                       fmaxf(fmaxf(b2.x, b2.y), fmaxf(b2.z, b2.w)));
      float contrib = mx * wv;
#pragma unroll
      for (int off = 1; off <= 16; off <<= 1) contrib += __shfl_xor(contrib, off);
      if (m == 0) res[h] = contrib + bw;
    }
    __syncthreads();
    if (tid < H_DIM)
      hf[(size_t)bid * H_DIM + tid] = res[tid];   // coalesced 512B store
  } else if (bid < 8224) {
    // ---- InstanceNorm1d(2ch over H) + Conv1d(2->16,k15,p7) ----
    const int b = bid - 8192;
    __shared__ float n0[H_DIM], n1[H_DIM];
    __shared__ float ws4[2][4];
    __shared__ float cw[480];
    for (int i = tid; i < 480; i += 256) cw[i] = conv_w[i];
    const int lane = tid & 63, wv2 = tid >> 6;
    float x0 = 0.f, x1 = 0.f;
    if (tid < 128) {
      x0 = prev[b * H_DIM + tid];
      x1 = cov[b * H_DIM + tid];
      x1 = fminf(fmaxf(x1, 0.0f), 1.0f);
      float s0 = x0, q0 = x0 * x0, s1 = x1, q1 = x1 * x1;
#pragma unroll
      for (int off = 32; off >= 1; off >>= 1) {
        s0 += __shfl_xor(s0, off); q0 += __shfl_xor(q0, off);
        s1 += __shfl_xor(s1, off); q1 += __shfl_xor(q1, off);
      }
      if (lane == 0) { ws4[wv2][0] = s0; ws4[wv2][1] = q0; ws4[wv2][2] = s1; ws4[wv2][3] = q1; }
    }
    __syncthreads();
    if (tid < 128) {
      float S0 = ws4[0][0] + ws4[1][0], Q0 = ws4[0][1] + ws4[1][1];
      float S1 = ws4[0][2] + ws4[1][2], Q1 = ws4[0][3] + ws4[1][3];
      const float rH = 1.0f / H_DIM;
      float mu0 = S0 * rH, mu1 = S1 * rH;
      float inv0 = 1.0f / sqrtf(Q0 * rH - mu0 * mu0 + 1e-5f);
      float inv1 = 1.0f / sqrtf(Q1 * rH - mu1 * mu1 + 1e-5f);
      n0[tid] = (x0 - mu0) * inv0;
      n1[tid] = (x1 - mu1) * inv1;
    }
    __syncthreads();
    if (tid < 128) {
      float o[16];
#pragma unroll
      for (int k = 0; k < 16; k++) o[k] = conv_b[k];
#pragma unroll
      for (int j = 0; j < 15; j++) {
        int hh = tid - 7 + j;
        if (hh >= 0 && hh < H_DIM) {
          float f0 = n0[hh], f1 = n1[hh];
#pragma unroll
          for (int k = 0; k < 16; k++)
            o[k] += f0 * cw[k * 30 + j] + f1 * cw[k * 30 + 15 + j];
        }
      }
      float* outp = convT + ((size_t)(b * H_DIM + tid)) * 16;
#pragma unroll
      for (int k = 0; k < 16; k++) outp[k] = o[k];
    }
  } else {
    // ---- hsum[b,a] = hidden[b,:] @ w_hid[:,a] + b_hid + b_enc + b_cb ----
    const int b = bid - 8224;
    const int a = tid;
    float acc = b_hid[a] + b_enc[a] + b_cb[a];
    const float* hb = hidden + b * 256;
#pragma unroll 4
    for (int d = 0; d < 256; d++) acc += hb[d] * w_hid[d * ATT_DIM + a];
    hsum[b * ATT_DIM + a] = acc;
  }
}

// ---------------------------------------------------------------------------
// KB: s = hf^T @ w_enc + convT @ w_cb + hsum; align = tanh(s) @ w_align + b
// 8 rows x 256 cols per block; thread t owns column a=t.  hf is (B,C,H).
__global__ __launch_bounds__(256) void kb_gemm_align(
    const float* __restrict__ hf, const float* __restrict__ convT,
    const float* __restrict__ hsum, const float* __restrict__ w_enc,
    const float* __restrict__ w_cb, const float* __restrict__ w_align,
    const float* __restrict__ b_align, float* __restrict__ align_out)
{
  __shared__ float At[C_DIM][12];   // [k=c][m], pitch 12 keeps float4 alignment
  __shared__ float Ct[16][9];       // [k][m]
  __shared__ float red[8][ATT_DIM];
  const int tid = threadIdx.x;
  const int m0 = blockIdx.x * 8;    // global row (b*H + h)
  const int b = m0 >> 7;
  const int h0 = m0 & 127;
  const float* hp = hf + ((size_t)(b * C_DIM + tid)) * H_DIM + h0;
  float4 r0 = *reinterpret_cast<const float4*>(hp);
  float4 r1 = *reinterpret_cast<const float4*>(hp + 4);
  *reinterpret_cast<float4*>(&At[tid][0]) = r0;
  *reinterpret_cast<float4*>(&At[tid][4]) = r1;
  if (tid < 128) {
    int m = tid >> 4, k = tid & 15;
    Ct[k][m] = convT[(size_t)(b * H_DIM + h0) * 16 + tid];
  }
  __syncthreads();
  float acc[8];
#pragma unroll
  for (int m = 0; m < 8; m++) acc[m] = 0.0f;
  const float* wep = w_enc + tid;
#pragma unroll 4
  for (int k = 0; k < C_DIM; k++) {
    float bv = wep[k * ATT_DIM];
    const float4 a0 = *reinterpret_cast<const float4*>(&At[k][0]);
    const float4 a1 = *reinterpret_cast<const float4*>(&At[k][4]);
    acc[0] += a0.x * bv; acc[1] += a0.y * bv; acc[2] += a0.z * bv; acc[3] += a0.w * bv;
    acc[4] += a1.x * bv; acc[5] += a1.y * bv; acc[6] += a1.z * bv; acc[7] += a1.w * bv;
  }
#pragma unroll
  for (int k = 0; k < 16; k++) {
    float bv = w_cb[k * ATT_DIM + tid];
#pragma unroll
    for (int m = 0; m < 8; m++) acc[m] += Ct[k][m] * bv;
  }
  const float hs = hsum[b * ATT_DIM + tid];
  const float wa = w_align[tid];
#pragma unroll
  for (int m = 0; m < 8; m++)
    red[m][tid] = tanhf(acc[m] + hs) * wa;
  __syncthreads();
  const int lane = tid & 63, wid = tid >> 6;
  const float ba = b_align[0];
  for (int m = wid; m < 8; m += 4) {
    float s = red[m][lane] + red[m][lane + 64] + red[m][lane + 128] + red[m][lane + 192];
#pragma unroll
    for (int off = 32; off >= 1; off >>= 1) s += __shfl_xor(s, off);
    if (lane == 0) align_out[m0 + m] = s + ba;
  }
}

// ---------------------------------------------------------------------------
// KC: in-block softmax over H (align is L2-resident) + context reduce.
// Dual accumulator streams for ILP; reverse block order for residual L3 hits.
__global__ __launch_bounds__(256) void kc_context(
    const float* __restrict__ feat, const float* __restrict__ align,
    float* __restrict__ attn_out, float* __restrict__ ctx)
{
  const int bc = 8191 - blockIdx.x;   // b*C + c, reversed
  const int b = bc >> 8, c = bc & 255;
  const int tid = threadIdx.x;
  __shared__ float al[H_DIM], at[H_DIM];
  if (tid < H_DIM) al[tid] = align[(b << 7) + tid];
  __syncthreads();
  if (tid < 64) {
    float a0 = al[tid], a1 = al[tid + 64];
    float mx = fmaxf(a0, a1);
#pragma unroll
    for (int off = 32; off >= 1; off >>= 1) mx = fmaxf(mx, __shfl_xor(mx, off));
    float e0 = expf(a0 - mx), e1 = expf(a1 - mx);
    float s = e0 + e1;
#pragma unroll
    for (int off = 32; off >= 1; off >>= 1) s += __shfl_xor(s, off);
    float inv = 1.0f / s;
    at[tid] = e0 * inv;
    at[tid + 64] = e1 * inv;
  }
  __syncthreads();
  if (c == 0 && tid < H_DIM) attn_out[(b << 7) + tid] = at[tid];
  const int g = tid >> 6, lane = tid & 63;
  const float* base = feat + (size_t)bc * H_DIM * W_DIM + lane * 4;
  float4 acc0 = make_float4(0.f, 0.f, 0.f, 0.f);
  float4 acc1 = make_float4(0.f, 0.f, 0.f, 0.f);
#pragma unroll 2
  for (int h = g; h < H_DIM; h += 8) {
    float4 v0 = *reinterpret_cast<const float4*>(base + (size_t)h * W_DIM);
    float4 v1 = *reinterpret_cast<const float4*>(base + (size_t)(h + 4) * W_DIM);
    float a0 = at[h], a1 = at[h + 4];
    acc0.x += v0.x * a0; acc0.y += v0.y * a0; acc0.z += v0.z * a0; acc0.w += v0.w * a0;
    acc1.x += v1.x * a1; acc1.y += v1.y * a1; acc1.z += v1.z * a1; acc1.w += v1.w * a1;
  }
  __shared__ float4 part[4][64];
  float4 acc;
  acc.x = acc0.x + acc1.x; acc.y = acc0.y + acc1.y;
  acc.z = acc0.z + acc1.z; acc.w = acc0.w + acc1.w;
  part[g][lane] = acc;
  __syncthreads();
  if (tid < 64) {
    float4 r0 = part[0][tid], r1 = part[1][tid], r2 = part[2][tid], r3 = part[3][tid];
    float4 o;
    o.x = r0.x + r1.x + r2.x + r3.x;
    o.y = r0.y + r1.y + r2.y + r3.y;
    o.z = r0.z + r1.z + r2.z + r3.z;
    o.w = r0.w + r1.w + r2.w + r3.w;
    *reinterpret_cast<float4*>(ctx + (size_t)bc * W_DIM + tid * 4) = o;
  }
}

// ---------------------------------------------------------------------------
extern "C" void kernel_launch(void* const* d_in, const int* in_sizes, int n_in,
                              void* d_out, int out_size, void* d_ws, size_t ws_size,
                              hipStream_t stream)
{
  const float* feat    = (const float*)d_in[0];
  const float* prev    = (const float*)d_in[1];
  const float* cov     = (const float*)d_in[2];
  const float* hidden  = (const float*)d_in[3];
  const float* w_width = (const float*)d_in[4];
  const float* b_width = (const float*)d_in[5];
  const float* w_enc   = (const float*)d_in[6];
  const float* b_enc   = (const float*)d_in[7];
  const float* conv_w  = (const float*)d_in[8];
  const float* conv_b  = (const float*)d_in[9];
  const float* w_cb    = (const float*)d_in[10];
  const float* b_cb    = (const float*)d_in[11];
  const float* w_hid   = (const float*)d_in[12];
  const float* b_hid   = (const float*)d_in[13];
  const float* w_align = (const float*)d_in[14];
  const float* b_align = (const float*)d_in[15];

  float* ctx_out  = (float*)d_out;                                   // (B,C,W)
  float* attn_out = (float*)d_out + (size_t)B_DIM * C_DIM * W_DIM;   // (B,H)

  float* ws    = (float*)d_ws;
  float* hf    = ws;                 // (B,C,H)  = 1048576 floats
  float* convT = hf + 1048576;       // (B,H,16) = 65536
  float* hsum  = convT + 65536;      // (B,ATT)  = 8192
  float* align = hsum + 8192;        // (B,H)    = 4096

  ka_fused<<<dim3(8192 + 32 + 32), dim3(256), 0, stream>>>(
      feat, w_width, b_width, prev, cov, conv_w, conv_b,
      hidden, w_hid, b_hid, b_enc, b_cb, hf, convT, hsum);
  kb_gemm_align<<<dim3((B_DIM * H_DIM) / 8), dim3(256), 0, stream>>>(
      hf, convT, hsum, w_enc, w_cb, w_align, b_align, align);
  kc_context<<<dim3(B_DIM * C_DIM), dim3(256), 0, stream>>>(
      feat, align, attn_out, ctx_out);
}